// Round 7
// baseline (315.558 us; speedup 1.0000x reference)
//
#include <hip/hip_runtime.h>
#include <hip/hip_bf16.h>
#include <hip/hip_fp8.h>

// Problem constants (from reference)
#define NN 50000          // nodes
#define EE 800000         // raw edges
#define E2 850000         // edges + self loops
#define F_IN 128
#define F_HID 64
#define NCHUNK ((NN + 255) / 256)   // 196
#define NTILE  ((NN + 63) / 64)     // 782
#define AGGB 2048                    // aggregate blocks (8192 waves resident)

// Radix partition parameters
#define PNB 32                       // dst-range bins (32%8==0: bucket->XCD consistent)
#define BCAP 32768                   // per-bin capacity (mean 25000, +50 sigma)
#define CBCH 512                     // edges per phase-A block
#define CBB ((EE + CBCH - 1) / CBCH) // 1563 blocks
#define CBCAP 48                     // per-bucket LDS staging (mean 16, huge slack + fallback)
#define SLICEB 64                    // per-bin slices for count/scatter (grid 2048)

__device__ __forceinline__ unsigned char f32_to_fp8(float x) {
    __hip_fp8_e4m3 t(x);              // OCP e4m3fn, saturating
    return t.__x;
}
__device__ __forceinline__ float fp8_to_f32(unsigned char b) {
    __hip_fp8_e4m3 t; t.__x = b;
    return (float)t;
}

// Single-VALU-op fp8->f32 with HW byte select (bit-identical to fp8_to_f32)
#if defined(__has_builtin)
#  if __has_builtin(__builtin_amdgcn_cvt_f32_fp8)
#    define CVT_FP8(v, s) __builtin_amdgcn_cvt_f32_fp8((v), (s))
#  endif
#endif
#ifndef CVT_FP8
#  define CVT_FP8(v, s) fp8_to_f32(((v) >> (8 * (s))) & 255)
#endif

// ---------------------------------------------------------------------------
// Phase A: ei float cast + 32-bin dst-range partition. NO global atomics on
// deg (that was ~25MB of memory-side RMW traffic in r5 + cross-XCD lines).
// LDS staging; flush is FLATTENED: one 32-entry prefix, every lane binary-
// searches its (bucket, idx) -> all 256 threads active, coalesced run writes.
// ---------------------------------------------------------------------------
__global__ __launch_bounds__(256) void cast_bin_kernel(const int* __restrict__ ei,
                                                       int* __restrict__ bin_cur,
                                                       unsigned long long* __restrict__ bins,
                                                       float* __restrict__ ei_out) {
    __shared__ unsigned long long buf[PNB * CBCAP];   // 12KB
    __shared__ int cnt[PNB];
    __shared__ int gbase[PNB];
    __shared__ int pfx[PNB + 1];
    int tid = threadIdx.x;
    if (tid < PNB) cnt[tid] = 0;
    __syncthreads();

    int e0 = blockIdx.x * CBCH;
    int e1 = e0 + CBCH; if (e1 > EE) e1 = EE;
    for (int e = e0 + tid; e < e1; e += 256) {
        int s = ei[e], d = ei[EE + e];
        ei_out[e]      = (float)s;
        ei_out[E2 + e] = (float)d;
        int b = (int)(((long long)d * PNB) / NN);
        unsigned long long pk = ((unsigned long long)(unsigned)d << 32) | (unsigned)s;
        int r = atomicAdd(&cnt[b], 1);
        if (r < CBCAP) buf[b * CBCAP + r] = pk;
        else {                                   // statistically unreachable fallback
            int p = atomicAdd(&bin_cur[b], 1);
            if (p < BCAP) bins[(size_t)b * BCAP + p] = pk;
        }
    }
    __syncthreads();
    if (tid < PNB) {
        int c = cnt[tid]; if (c > CBCAP) c = CBCAP;
        cnt[tid] = c;
        gbase[tid] = c ? atomicAdd(&bin_cur[tid], c) : 0;
    }
    __syncthreads();
    if (tid == 0) {
        int run = 0;
        for (int b = 0; b < PNB; ++b) { pfx[b] = run; run += cnt[b]; }
        pfx[PNB] = run;
    }
    __syncthreads();
    int total = pfx[PNB];
    for (int idx = tid; idx < total; idx += 256) {
        int lo = 0, hi = PNB;                    // 5-step binary search
        while (hi - lo > 1) { int mid = (lo + hi) >> 1; if (pfx[mid] <= idx) lo = mid; else hi = mid; }
        int b = lo, li = idx - pfx[b];
        int p = gbase[b] + li;
        if (p < BCAP) bins[(size_t)b * BCAP + p] = buf[b * CBCAP + li];
    }
}

// ---------------------------------------------------------------------------
// Degree count from compacted bins. bucket = blockIdx&31 (XCD-consistent):
// each bucket's deg window is ~6KB in ONE XCD's L2 -> atomics L2-local.
// ---------------------------------------------------------------------------
__global__ __launch_bounds__(256) void count_bins(const int* __restrict__ bin_cur,
                                                  const unsigned long long* __restrict__ bins,
                                                  int* __restrict__ deg) {
    int b = blockIdx.x & (PNB - 1);
    int slice = blockIdx.x >> 5;          // 0..SLICEB-1
    int cnt = bin_cur[b];
    if (cnt > BCAP) cnt = BCAP;
    const unsigned long long* bp = bins + (size_t)b * BCAP;
    for (int i = slice * 256 + threadIdx.x; i < cnt; i += SLICEB * 256) {
        int d = (int)(bp[i] >> 32);
        atomicAdd(&deg[d], 1);
    }
}

// ---------------------------------------------------------------------------
// Fused hierarchical scan, stage 1+2. Degree used everywhere is deg[i]+1
// (the +1 is the analytic self-loop).
// ---------------------------------------------------------------------------
__global__ __launch_bounds__(256) void scan_part12(const int* __restrict__ deg,
                                                   int* __restrict__ csum,
                                                   int* __restrict__ ticket) {
    int i = blockIdx.x * 256 + threadIdx.x;
    int v = (i < NN) ? deg[i] + 1 : 0;
#pragma unroll
    for (int d = 32; d; d >>= 1) v += __shfl_xor(v, d);
    __shared__ int ws[4];
    if ((threadIdx.x & 63) == 0) ws[threadIdx.x >> 6] = v;
    __syncthreads();
    __shared__ int isLast;
    if (threadIdx.x == 0) {
        atomicExch(&csum[blockIdx.x], ws[0] + ws[1] + ws[2] + ws[3]);
        __threadfence();
        isLast = (atomicAdd(ticket, 1) == gridDim.x - 1) ? 1 : 0;
    }
    __syncthreads();
    if (isLast) {
        __threadfence();
        __shared__ int sd[256];
        int t = threadIdx.x;
        int v2 = (t < NCHUNK) ? atomicAdd(&csum[t], 0) : 0;
        sd[t] = v2;
        __syncthreads();
        for (int off = 1; off < 256; off <<= 1) {
            int o = (t >= off) ? sd[t - off] : 0;
            __syncthreads();
            sd[t] += o;
            __syncthreads();
        }
        if (t < NCHUNK) atomicExch(&csum[t], sd[t] - v2);   // exclusive
    }
}

// scan_part3 PRE-PLACES the self-loop: src_sorted[offs[i]] = i, cursor starts
// at offs[i]+1, and writes the self-loop slice of ei_out. Segment-internal
// order is irrelevant (order-independent sum; alpha uses original edge order).
__global__ __launch_bounds__(256) void scan_part3(const int* __restrict__ deg,
                                                  const int* __restrict__ csum,
                                                  int* __restrict__ offs,
                                                  int* __restrict__ cursor,
                                                  int* __restrict__ src_sorted,
                                                  float* __restrict__ ei_out) {
    __shared__ int sd[256];
    int t = threadIdx.x;
    int i = blockIdx.x * 256 + t;
    int v = (i < NN) ? deg[i] + 1 : 0;
    sd[t] = v;
    __syncthreads();
    for (int off = 1; off < 256; off <<= 1) {
        int o = (t >= off) ? sd[t - off] : 0;
        __syncthreads();
        sd[t] += o;
        __syncthreads();
    }
    if (i < NN) {
        int ex = sd[t] - v + csum[blockIdx.x];
        offs[i] = ex;
        cursor[i] = ex + 1;          // slot ex holds the self-loop
        src_sorted[ex] = i;
        ei_out[EE + i]      = (float)i;
        ei_out[E2 + EE + i] = (float)i;
    }
}

// ---------------------------------------------------------------------------
// Phase B scatter (r2-measured ~13us): bucket = blockIdx&31; 32%8==0 so all
// blocks of one bucket land on the same XCD -> cursor atomics and src_sorted
// writes confined to a ~425KB window in ONE L2; lines fill before write-back.
// ---------------------------------------------------------------------------
__global__ __launch_bounds__(256) void scatter_bins(const int* __restrict__ bin_cur,
                                                    const unsigned long long* __restrict__ bins,
                                                    int* __restrict__ cursor,
                                                    int* __restrict__ src_sorted) {
    int b = blockIdx.x & (PNB - 1);
    int slice = blockIdx.x >> 5;          // 0..SLICEB-1
    int cnt = bin_cur[b];
    if (cnt > BCAP) cnt = BCAP;
    const unsigned long long* bp = bins + (size_t)b * BCAP;
    for (int i = slice * 256 + threadIdx.x; i < cnt; i += SLICEB * 256) {
        unsigned long long v = bp[i];
        int d = (int)(v >> 32);
        int s = (int)(v & 0xffffffffu);
        int pos = atomicAdd(&cursor[d], 1);
        src_sorted[pos] = s;
    }
}

// ---------------------------------------------------------------------------
// Tiled fp32 GEMM: z_fp8[64-row tile] = h_tile(64xK) @ W(Kx64), fused
// es = z.a_src, ed = z.a_dst (per-row, fp32) in the epilogue.
// ---------------------------------------------------------------------------
template <int K>
__global__ __launch_bounds__(256) void gemm_tile(const float* __restrict__ h,
                                                 const float* __restrict__ W,
                                                 const float* __restrict__ a_src,
                                                 const float* __restrict__ a_dst,
                                                 unsigned char* __restrict__ z8,
                                                 float* __restrict__ es,
                                                 float* __restrict__ ed) {
    constexpr int LDA = K + 4;              // pad keeps 16B alignment, breaks pow2 stride
    __shared__ float Alds[64 * LDA];
    __shared__ float Blds[K * 64];

    int tid = threadIdx.x;
    int base = blockIdx.x * 64;

    // Stage A-tile (64 x K) with coalesced float4 loads
    {
        constexpr int F4R = K / 4;          // float4 per row: 32 or 16
        for (int t = tid; t < 64 * F4R; t += 256) {
            int r = t / F4R;
            int c4 = t % F4R;
            int gr = base + r;
            if (gr >= NN) gr = NN - 1;      // clamp; stores are guarded later
            float4 v = *(const float4*)(h + (size_t)gr * K + c4 * 4);
            *(float4*)(&Alds[r * LDA + c4 * 4]) = v;
        }
    }
    // Stage B (K x 64) — flat copy
    for (int t = tid; t < K * 16; t += 256) {
        float4 v = *(const float4*)(W + t * 4);
        *(float4*)(&Blds[t * 4]) = v;
    }
    __syncthreads();

    int tx = tid & 15;                      // col group: cols 4*tx..4*tx+3
    int ty = tid >> 4;                      // row group: rows 4*ty..4*ty+3

    float acc[4][4] = {};
#pragma unroll 4
    for (int k = 0; k < K; k += 4) {
        float4 a[4], b[4];
#pragma unroll
        for (int i = 0; i < 4; ++i)
            a[i] = *(const float4*)(&Alds[(4 * ty + i) * LDA + k]);
#pragma unroll
        for (int kk = 0; kk < 4; ++kk)
            b[kk] = *(const float4*)(&Blds[(k + kk) * 64 + 4 * tx]);
#pragma unroll
        for (int i = 0; i < 4; ++i) {
            acc[i][0] = fmaf(a[i].x, b[0].x, acc[i][0]);
            acc[i][1] = fmaf(a[i].x, b[0].y, acc[i][1]);
            acc[i][2] = fmaf(a[i].x, b[0].z, acc[i][2]);
            acc[i][3] = fmaf(a[i].x, b[0].w, acc[i][3]);
            acc[i][0] = fmaf(a[i].y, b[1].x, acc[i][0]);
            acc[i][1] = fmaf(a[i].y, b[1].y, acc[i][1]);
            acc[i][2] = fmaf(a[i].y, b[1].z, acc[i][2]);
            acc[i][3] = fmaf(a[i].y, b[1].w, acc[i][3]);
            acc[i][0] = fmaf(a[i].z, b[2].x, acc[i][0]);
            acc[i][1] = fmaf(a[i].z, b[2].y, acc[i][1]);
            acc[i][2] = fmaf(a[i].z, b[2].z, acc[i][2]);
            acc[i][3] = fmaf(a[i].z, b[2].w, acc[i][3]);
            acc[i][0] = fmaf(a[i].w, b[3].x, acc[i][0]);
            acc[i][1] = fmaf(a[i].w, b[3].y, acc[i][1]);
            acc[i][2] = fmaf(a[i].w, b[3].z, acc[i][2]);
            acc[i][3] = fmaf(a[i].w, b[3].w, acc[i][3]);
        }
    }

    // Epilogue: store fp8 z rows, fold es/ed partial dots, reduce across tx group
    float4 as4 = *(const float4*)(a_src + 4 * tx);
    float4 ad4 = *(const float4*)(a_dst + 4 * tx);
    float ps[4], pd[4];
#pragma unroll
    for (int i = 0; i < 4; ++i) {
        int gr = base + 4 * ty + i;
        if (gr < NN) {
            unsigned int pk = (unsigned int)f32_to_fp8(acc[i][0])
                            | ((unsigned int)f32_to_fp8(acc[i][1]) << 8)
                            | ((unsigned int)f32_to_fp8(acc[i][2]) << 16)
                            | ((unsigned int)f32_to_fp8(acc[i][3]) << 24);
            *(unsigned int*)(&z8[(size_t)gr * 64 + 4 * tx]) = pk;
        }
        ps[i] = acc[i][0] * as4.x + acc[i][1] * as4.y + acc[i][2] * as4.z + acc[i][3] * as4.w;
        pd[i] = acc[i][0] * ad4.x + acc[i][1] * ad4.y + acc[i][2] * ad4.z + acc[i][3] * ad4.w;
    }
#pragma unroll
    for (int d = 1; d < 16; d <<= 1) {
#pragma unroll
        for (int i = 0; i < 4; ++i) {
            ps[i] += __shfl_xor(ps[i], d);
            pd[i] += __shfl_xor(pd[i], d);
        }
    }
    if (tx == 0) {
#pragma unroll
        for (int i = 0; i < 4; ++i) {
            int gr = base + 4 * ty + i;
            if (gr < NN) { es[gr] = ps[i]; ed[gr] = pd[i]; }
        }
    }
}

// ---------------------------------------------------------------------------
// Pipelined multi-node aggregation, dword-vectorized z8 gather (r4 version;
// deg excludes the analytic self-loop -> dg = deg[n] + 1).
// ---------------------------------------------------------------------------
__global__ __launch_bounds__(256) void aggregate(const int* __restrict__ offs,
                                                 const int* __restrict__ deg,
                                                 const int* __restrict__ src_sorted,
                                                 const float* __restrict__ es,
                                                 const float* __restrict__ ed,
                                                 const unsigned char* __restrict__ z8,
                                                 const float* __restrict__ bias,
                                                 float* __restrict__ hout,
                                                 float* __restrict__ denom_out) {
    int tid = threadIdx.x;
    int lane = tid & 63;
    int wave = blockIdx.x * 4 + (tid >> 6);
    const int NW = AGGB * 4;

    int sub  = lane >> 4;          // edge slot within 4-edge group
    int fgrp = (lane & 15) * 4;    // first of this lane's 4 features
    const unsigned char* zp = z8 + fgrp;
    float4 bi4 = *(const float4*)(bias + fgrp);

    int n = wave;
    if (n >= NN) return;
    n = __builtin_amdgcn_readfirstlane(n);
    int off = offs[n];
    int dg = deg[n] + 1;
    float edn = ed[n];
    int sv = src_sorted[off + ((lane < dg) ? lane : 0)];   // first batch src
    float ese = es[sv];                                    // first batch es

    while (true) {
        // Issue next node's metadata loads early (overlap with processing)
        int n2 = n + NW;
        bool more = (n2 < NN);
        int off2 = 0, dg2 = 0; float edn2 = 0.f;
        if (more) {
            n2 = __builtin_amdgcn_readfirstlane(n2);
            off2 = offs[n2]; dg2 = deg[n2] + 1; edn2 = ed[n2];
        }

        // ---- process node n ----
        float dsum = 0.f;
        float a0 = 0.f, a1 = 0.f, a2 = 0.f, a3 = 0.f;
        for (int b0 = 0; b0 < dg; b0 += 64) {
            int bl = dg - b0; if (bl > 64) bl = 64;
            int svb; float esv;
            if (b0 == 0) { svb = sv; esv = ese; }          // prefetched
            else {
                svb = src_sorted[off + b0 + ((lane < bl) ? lane : 0)];
                esv = es[svb];
            }
            float e = esv + edn;
            e = (e > 0.f) ? e : 0.2f * e;
            float w = (lane < bl) ? __expf(e) : 0.f;   // w=0 pads tail edges
            dsum += w;

            int ng = (bl + 3) >> 2;        // 4-edge groups in this batch
            int j = 0;
            for (; j + 4 <= ng; j += 4) {  // 16 edges, 4 loads in flight
                int i0 = 4 * j + sub;
                int   s0 = __shfl(svb, i0);
                int   s1 = __shfl(svb, i0 + 4);
                int   s2 = __shfl(svb, i0 + 8);
                int   s3 = __shfl(svb, i0 + 12);
                unsigned int v0 = *(const unsigned int*)(zp + (size_t)s0 * 64);
                unsigned int v1 = *(const unsigned int*)(zp + (size_t)s1 * 64);
                unsigned int v2 = *(const unsigned int*)(zp + (size_t)s2 * 64);
                unsigned int v3 = *(const unsigned int*)(zp + (size_t)s3 * 64);
                float w0 = __shfl(w, i0);
                float w1 = __shfl(w, i0 + 4);
                float w2 = __shfl(w, i0 + 8);
                float w3 = __shfl(w, i0 + 12);
                a0 = fmaf(w0, CVT_FP8(v0, 0), a0);
                a1 = fmaf(w0, CVT_FP8(v0, 1), a1);
                a2 = fmaf(w0, CVT_FP8(v0, 2), a2);
                a3 = fmaf(w0, CVT_FP8(v0, 3), a3);
                a0 = fmaf(w1, CVT_FP8(v1, 0), a0);
                a1 = fmaf(w1, CVT_FP8(v1, 1), a1);
                a2 = fmaf(w1, CVT_FP8(v1, 2), a2);
                a3 = fmaf(w1, CVT_FP8(v1, 3), a3);
                a0 = fmaf(w2, CVT_FP8(v2, 0), a0);
                a1 = fmaf(w2, CVT_FP8(v2, 1), a1);
                a2 = fmaf(w2, CVT_FP8(v2, 2), a2);
                a3 = fmaf(w2, CVT_FP8(v2, 3), a3);
                a0 = fmaf(w3, CVT_FP8(v3, 0), a0);
                a1 = fmaf(w3, CVT_FP8(v3, 1), a1);
                a2 = fmaf(w3, CVT_FP8(v3, 2), a2);
                a3 = fmaf(w3, CVT_FP8(v3, 3), a3);
            }
            for (; j < ng; ++j) {          // remaining 4-edge groups
                int i0 = 4 * j + sub;
                int   s0 = __shfl(svb, i0);
                unsigned int v0 = *(const unsigned int*)(zp + (size_t)s0 * 64);
                float w0 = __shfl(w, i0);
                a0 = fmaf(w0, CVT_FP8(v0, 0), a0);
                a1 = fmaf(w0, CVT_FP8(v0, 1), a1);
                a2 = fmaf(w0, CVT_FP8(v0, 2), a2);
                a3 = fmaf(w0, CVT_FP8(v0, 3), a3);
            }
        }

        // Prefetch next node's first src batch (hides behind epilogue)
        int sv2 = 0;
        if (more) sv2 = src_sorted[off2 + ((lane < dg2) ? lane : 0)];

        // Epilogue: fold edge-subsets (lanes l, l+16, l+32, l+48), reduce denom
        a0 += __shfl_xor(a0, 16); a1 += __shfl_xor(a1, 16);
        a2 += __shfl_xor(a2, 16); a3 += __shfl_xor(a3, 16);
        a0 += __shfl_xor(a0, 32); a1 += __shfl_xor(a1, 32);
        a2 += __shfl_xor(a2, 32); a3 += __shfl_xor(a3, 32);
#pragma unroll
        for (int d = 32; d; d >>= 1) dsum += __shfl_xor(dsum, d);

        // Prefetch next node's es gather
        float ese2 = 0.f;
        if (more) ese2 = es[sv2];

        float inv = 1.f / (dsum + 1e-16f);
        if (lane < 16) {
            float4 o;
            o.x = a0 * inv + bi4.x;
            o.y = a1 * inv + bi4.y;
            o.z = a2 * inv + bi4.z;
            o.w = a3 * inv + bi4.w;
            o.x = (o.x > 0.f) ? o.x : 0.01f * o.x;
            o.y = (o.y > 0.f) ? o.y : 0.01f * o.y;
            o.z = (o.z > 0.f) ? o.z : 0.01f * o.z;
            o.w = (o.w > 0.f) ? o.w : 0.01f * o.w;
            *(float4*)(hout + (size_t)n * 64 + fgrp) = o;
        }
        if (lane == 0) denom_out[n] = dsum;

        if (!more) break;
        n = n2; off = off2; dg = dg2; edn = edn2; sv = sv2; ese = ese2;
    }
}

// ---------------------------------------------------------------------------
// Alpha in ORIGINAL edge order: contiguous writes, L2-resident gathers.
// ---------------------------------------------------------------------------
__global__ __launch_bounds__(256) void alpha_kernel(const int* __restrict__ ei,
                                                    const float* __restrict__ es,
                                                    const float* __restrict__ ed,
                                                    const float* __restrict__ denom,
                                                    float* __restrict__ alpha_out) {
    int e = blockIdx.x * 256 + threadIdx.x;
    if (e >= E2) return;
    int s, d;
    if (e < EE) { s = ei[e]; d = ei[EE + e]; }
    else        { s = d = e - EE; }
    float x = es[s] + ed[d];
    x = (x > 0.f) ? x : 0.2f * x;
    alpha_out[e] = __expf(x) / (denom[d] + 1e-16f);
}

// ---------------------------------------------------------------------------
extern "C" void kernel_launch(void* const* d_in, const int* in_sizes, int n_in,
                              void* d_out, int out_size, void* d_ws, size_t ws_size,
                              hipStream_t stream) {
    const float* x   = (const float*)d_in[0];
    const int*   ei  = (const int*)d_in[1];
    const float* W1  = (const float*)d_in[2];
    const float* as1 = (const float*)d_in[3];
    const float* ad1 = (const float*)d_in[4];
    const float* b1  = (const float*)d_in[5];
    const float* W2  = (const float*)d_in[6];
    const float* as2 = (const float*)d_in[7];
    const float* ad2 = (const float*)d_in[8];
    const float* b2  = (const float*)d_in[9];
    const float* W3  = (const float*)d_in[10];
    const float* as3 = (const float*)d_in[11];
    const float* ad3 = (const float*)d_in[12];
    const float* b3  = (const float*)d_in[13];

    // d_out is float32 (reference output dtype): h | ei | alpha, flat.
    float* out       = (float*)d_out;
    float* h_out     = out;                                // NN*64
    float* ei_out    = out + (size_t)NN * 64;              // 2*E2
    float* alpha_out = ei_out + 2 * (size_t)E2;            // E2

    // Workspace carve-up
    char* w = (char*)d_ws;
    auto carve = [&](size_t bytes) {
        void* p = (void*)w;
        w += (bytes + 255) & ~size_t(255);
        return p;
    };
    float* h1  = (float*)carve((size_t)NN * 64 * 4);
    float* h2  = (float*)carve((size_t)NN * 64 * 4);
    unsigned char* z8 = (unsigned char*)carve((size_t)NN * 64);
    float* es  = (float*)carve((size_t)NN * 4);
    float* ed  = (float*)carve((size_t)NN * 4);
    float* denom = (float*)carve((size_t)NN * 4);
    int* deg        = (int*)carve(((size_t)NN + 64) * 4);  // deg + ticket + bin_cur (zeroed together)
    int* ticket     = deg + NN;
    int* bin_cur    = deg + NN + 1;                        // 32 ints
    int* offs       = (int*)carve((size_t)NN * 4);
    int* cursor     = (int*)carve((size_t)NN * 4);
    int* csum       = (int*)carve((size_t)NCHUNK * 4);
    int* src_sorted = (int*)carve((size_t)E2 * 4);
    unsigned long long* bins = (unsigned long long*)carve((size_t)PNB * BCAP * 8);

    const int EB = (E2 + 255) / 256;       // 3321

    hipMemsetAsync(deg, 0, ((size_t)NN + 64) * 4, stream);
    cast_bin_kernel<<<CBB, 256, 0, stream>>>(ei, bin_cur, bins, ei_out);
    count_bins<<<PNB * SLICEB, 256, 0, stream>>>(bin_cur, bins, deg);
    scan_part12<<<NCHUNK, 256, 0, stream>>>(deg, csum, ticket);
    scan_part3<<<NCHUNK, 256, 0, stream>>>(deg, csum, offs, cursor, src_sorted, ei_out);
    scatter_bins<<<PNB * SLICEB, 256, 0, stream>>>(bin_cur, bins, cursor, src_sorted);

    // Layer 1: x (K=128) -> h1
    gemm_tile<F_IN><<<NTILE, 256, 0, stream>>>(x, W1, as1, ad1, z8, es, ed);
    aggregate<<<AGGB, 256, 0, stream>>>(offs, deg, src_sorted, es, ed, z8, b1, h1, denom);
    // Layer 2: h1 (K=64) -> h2
    gemm_tile<F_HID><<<NTILE, 256, 0, stream>>>(h1, W2, as2, ad2, z8, es, ed);
    aggregate<<<AGGB, 256, 0, stream>>>(offs, deg, src_sorted, es, ed, z8, b2, h2, denom);
    // Layer 3: h2 (K=64) -> d_out h (fp32) + alpha
    gemm_tile<F_HID><<<NTILE, 256, 0, stream>>>(h2, W3, as3, ad3, z8, es, ed);
    aggregate<<<AGGB, 256, 0, stream>>>(offs, deg, src_sorted, es, ed, z8, b3, h_out, denom);
    alpha_kernel<<<EB, 256, 0, stream>>>(ei, es, ed, denom, alpha_out);
}

// Round 8
// 301.073 us; speedup vs baseline: 1.0481x; 1.0481x over previous
//
#include <hip/hip_runtime.h>
#include <hip/hip_bf16.h>
#include <hip/hip_fp8.h>

// Problem constants (from reference)
#define NN 50000          // nodes
#define EE 800000         // raw edges
#define E2 850000         // edges + self loops
#define F_IN 128
#define F_HID 64
#define NCHUNK ((NN + 255) / 256)   // 196
#define NTILE  ((NN + 63) / 64)     // 782
#define AGGB 2048                    // aggregate blocks (8192 waves resident)
#define SLICES 512
#define SCHUNK ((E2 + SLICES - 1) / SLICES)  // 1661

__device__ __forceinline__ unsigned char f32_to_fp8(float x) {
    __hip_fp8_e4m3 t(x);              // OCP e4m3fn, saturating
    return t.__x;
}
__device__ __forceinline__ float fp8_to_f32(unsigned char b) {
    __hip_fp8_e4m3 t; t.__x = b;
    return (float)t;
}

// Single-VALU-op fp8->f32 with HW byte select (bit-identical to fp8_to_f32)
#if defined(__has_builtin)
#  if __has_builtin(__builtin_amdgcn_cvt_f32_fp8)
#    define CVT_FP8(v, s) __builtin_amdgcn_cvt_f32_fp8((v), (s))
#  endif
#endif
#ifndef CVT_FP8
#  define CVT_FP8(v, s) fp8_to_f32(((v) >> (8 * (s))) & 255)
#endif

// ---------------------------------------------------------------------------
// Histogram of dst degrees + write ei output (float cast of int edge list)
// ---------------------------------------------------------------------------
__global__ __launch_bounds__(256) void hist_ei_kernel(const int* __restrict__ ei,
                                                      int* __restrict__ deg,
                                                      float* __restrict__ ei_out) {
    int e = blockIdx.x * 256 + threadIdx.x;
    if (e >= E2) return;
    int s, d;
    if (e < EE) { s = ei[e]; d = ei[EE + e]; }
    else        { s = d = e - EE; }
    atomicAdd(&deg[d], 1);
    ei_out[e]      = (float)s;
    ei_out[E2 + e] = (float)d;
}

// ---------------------------------------------------------------------------
// Fused hierarchical scan, stage 1+2: per-block sums -> csum; last block
// (device-scope ticket) scans csum in-place. Atomics used for csum handoff
// (bypass per-XCD L2 non-coherence).
// ---------------------------------------------------------------------------
__global__ __launch_bounds__(256) void scan_part12(const int* __restrict__ deg,
                                                   int* __restrict__ csum,
                                                   int* __restrict__ ticket) {
    int i = blockIdx.x * 256 + threadIdx.x;
    int v = (i < NN) ? deg[i] : 0;
#pragma unroll
    for (int d = 32; d; d >>= 1) v += __shfl_xor(v, d);
    __shared__ int ws[4];
    if ((threadIdx.x & 63) == 0) ws[threadIdx.x >> 6] = v;
    __syncthreads();
    __shared__ int isLast;
    if (threadIdx.x == 0) {
        atomicExch(&csum[blockIdx.x], ws[0] + ws[1] + ws[2] + ws[3]);
        __threadfence();
        isLast = (atomicAdd(ticket, 1) == gridDim.x - 1) ? 1 : 0;
    }
    __syncthreads();
    if (isLast) {
        __threadfence();
        __shared__ int sd[256];
        int t = threadIdx.x;
        int v2 = (t < NCHUNK) ? atomicAdd(&csum[t], 0) : 0;
        sd[t] = v2;
        __syncthreads();
        for (int off = 1; off < 256; off <<= 1) {
            int o = (t >= off) ? sd[t - off] : 0;
            __syncthreads();
            sd[t] += o;
            __syncthreads();
        }
        if (t < NCHUNK) atomicExch(&csum[t], sd[t] - v2);   // exclusive
    }
}

__global__ __launch_bounds__(256) void scan_part3(const int* __restrict__ deg,
                                                  const int* __restrict__ csum,
                                                  int* __restrict__ offs,
                                                  int* __restrict__ cursor) {
    __shared__ int sd[256];
    int t = threadIdx.x;
    int i = blockIdx.x * 256 + t;
    int v = (i < NN) ? deg[i] : 0;
    sd[t] = v;
    __syncthreads();
    for (int off = 1; off < 256; off <<= 1) {
        int o = (t >= off) ? sd[t - off] : 0;
        __syncthreads();
        sd[t] += o;
        __syncthreads();
    }
    if (i < NN) {
        int ex = sd[t] - v + csum[blockIdx.x];
        offs[i] = ex;
        cursor[i] = ex;
    }
}

// ---------------------------------------------------------------------------
// Bucketed counting-sort scatter: 8 dst-range buckets, one per blockIdx&7.
// blockIdx&7 maps round-robin to XCDs, so each bucket's cursor atomics and
// src_sorted writes (~1.7MB dst window) stay in ONE XCD's L2. d-only
// prefilter: the s row is loaded only for matching-bucket lanes (~1/8).
// ---------------------------------------------------------------------------
__global__ __launch_bounds__(256) void scatter_kernel(const int* __restrict__ ei,
                                                      int* __restrict__ cursor,
                                                      int* __restrict__ src_sorted) {
    int g = blockIdx.x & 7;
    int slice = blockIdx.x >> 3;
    int begin = slice * SCHUNK;
    int end = begin + SCHUNK; if (end > E2) end = E2;
    for (int e = begin + threadIdx.x; e < end; e += 256) {
        int d = (e < EE) ? ei[EE + e] : e - EE;
        int bucket = (d * 8) / NN;             // contiguous dst ranges
        if (bucket == g) {
            int s = (e < EE) ? ei[e] : e - EE;
            int pos = atomicAdd(&cursor[d], 1);
            src_sorted[pos] = s;
        }
    }
}

// ---------------------------------------------------------------------------
// Tiled fp32 GEMM: z_fp8[64-row tile] = h_tile(64xK) @ W(Kx64), fused
// es = z.a_src, ed = z.a_dst (per-row, fp32) in the epilogue.
// ---------------------------------------------------------------------------
template <int K>
__global__ __launch_bounds__(256) void gemm_tile(const float* __restrict__ h,
                                                 const float* __restrict__ W,
                                                 const float* __restrict__ a_src,
                                                 const float* __restrict__ a_dst,
                                                 unsigned char* __restrict__ z8,
                                                 float* __restrict__ es,
                                                 float* __restrict__ ed) {
    constexpr int LDA = K + 4;              // pad keeps 16B alignment, breaks pow2 stride
    __shared__ float Alds[64 * LDA];
    __shared__ float Blds[K * 64];

    int tid = threadIdx.x;
    int base = blockIdx.x * 64;

    // Stage A-tile (64 x K) with coalesced float4 loads
    {
        constexpr int F4R = K / 4;          // float4 per row: 32 or 16
        for (int t = tid; t < 64 * F4R; t += 256) {
            int r = t / F4R;
            int c4 = t % F4R;
            int gr = base + r;
            if (gr >= NN) gr = NN - 1;      // clamp; stores are guarded later
            float4 v = *(const float4*)(h + (size_t)gr * K + c4 * 4);
            *(float4*)(&Alds[r * LDA + c4 * 4]) = v;
        }
    }
    // Stage B (K x 64) — flat copy
    for (int t = tid; t < K * 16; t += 256) {
        float4 v = *(const float4*)(W + t * 4);
        *(float4*)(&Blds[t * 4]) = v;
    }
    __syncthreads();

    int tx = tid & 15;                      // col group: cols 4*tx..4*tx+3
    int ty = tid >> 4;                      // row group: rows 4*ty..4*ty+3

    float acc[4][4] = {};
#pragma unroll 4
    for (int k = 0; k < K; k += 4) {
        float4 a[4], b[4];
#pragma unroll
        for (int i = 0; i < 4; ++i)
            a[i] = *(const float4*)(&Alds[(4 * ty + i) * LDA + k]);
#pragma unroll
        for (int kk = 0; kk < 4; ++kk)
            b[kk] = *(const float4*)(&Blds[(k + kk) * 64 + 4 * tx]);
#pragma unroll
        for (int i = 0; i < 4; ++i) {
            acc[i][0] = fmaf(a[i].x, b[0].x, acc[i][0]);
            acc[i][1] = fmaf(a[i].x, b[0].y, acc[i][1]);
            acc[i][2] = fmaf(a[i].x, b[0].z, acc[i][2]);
            acc[i][3] = fmaf(a[i].x, b[0].w, acc[i][3]);
            acc[i][0] = fmaf(a[i].y, b[1].x, acc[i][0]);
            acc[i][1] = fmaf(a[i].y, b[1].y, acc[i][1]);
            acc[i][2] = fmaf(a[i].y, b[1].z, acc[i][2]);
            acc[i][3] = fmaf(a[i].y, b[1].w, acc[i][3]);
            acc[i][0] = fmaf(a[i].z, b[2].x, acc[i][0]);
            acc[i][1] = fmaf(a[i].z, b[2].y, acc[i][1]);
            acc[i][2] = fmaf(a[i].z, b[2].z, acc[i][2]);
            acc[i][3] = fmaf(a[i].z, b[2].w, acc[i][3]);
            acc[i][0] = fmaf(a[i].w, b[3].x, acc[i][0]);
            acc[i][1] = fmaf(a[i].w, b[3].y, acc[i][1]);
            acc[i][2] = fmaf(a[i].w, b[3].z, acc[i][2]);
            acc[i][3] = fmaf(a[i].w, b[3].w, acc[i][3]);
        }
    }

    // Epilogue: store fp8 z rows, fold es/ed partial dots, reduce across tx group
    float4 as4 = *(const float4*)(a_src + 4 * tx);
    float4 ad4 = *(const float4*)(a_dst + 4 * tx);
    float ps[4], pd[4];
#pragma unroll
    for (int i = 0; i < 4; ++i) {
        int gr = base + 4 * ty + i;
        if (gr < NN) {
            unsigned int pk = (unsigned int)f32_to_fp8(acc[i][0])
                            | ((unsigned int)f32_to_fp8(acc[i][1]) << 8)
                            | ((unsigned int)f32_to_fp8(acc[i][2]) << 16)
                            | ((unsigned int)f32_to_fp8(acc[i][3]) << 24);
            *(unsigned int*)(&z8[(size_t)gr * 64 + 4 * tx]) = pk;
        }
        ps[i] = acc[i][0] * as4.x + acc[i][1] * as4.y + acc[i][2] * as4.z + acc[i][3] * as4.w;
        pd[i] = acc[i][0] * ad4.x + acc[i][1] * ad4.y + acc[i][2] * ad4.z + acc[i][3] * ad4.w;
    }
#pragma unroll
    for (int d = 1; d < 16; d <<= 1) {
#pragma unroll
        for (int i = 0; i < 4; ++i) {
            ps[i] += __shfl_xor(ps[i], d);
            pd[i] += __shfl_xor(pd[i], d);
        }
    }
    if (tx == 0) {
#pragma unroll
        for (int i = 0; i < 4; ++i) {
            int gr = base + 4 * ty + i;
            if (gr < NN) { es[gr] = ps[i]; ed[gr] = pd[i]; }
        }
    }
}

// ---------------------------------------------------------------------------
// Pipelined multi-node aggregation. Inner-loop cross-lane traffic replaced:
// instead of 8 shfl broadcasts per 4-edge group (4 src + 4 weight — the
// dominant DS cost), each batch publishes packed (w_bits<<32 | s*64) ONCE
// per lane to a per-wave 64xu64 LDS slice; the gather loop reads group j's
// pair with a single broadcast ds_read_b64 (16-lane groups hit the same
// address -> conflict-free). 8x fewer DS ops. Wave-private slice: no
// __syncthreads, ordering via lgkmcnt. Values/arith order bit-identical.
// ---------------------------------------------------------------------------
__global__ __launch_bounds__(256) void aggregate(const int* __restrict__ offs,
                                                 const int* __restrict__ deg,
                                                 const int* __restrict__ src_sorted,
                                                 const float* __restrict__ es,
                                                 const float* __restrict__ ed,
                                                 const unsigned char* __restrict__ z8,
                                                 const float* __restrict__ bias,
                                                 float* __restrict__ hout,
                                                 float* __restrict__ denom_out) {
    __shared__ unsigned long long swl[4][64];   // per-wave publish slice (2KB)
    int tid = threadIdx.x;
    int lane = tid & 63;
    int wslot = tid >> 6;
    int wave = blockIdx.x * 4 + wslot;
    const int NW = AGGB * 4;

    int sub  = lane >> 4;          // edge slot within 4-edge group
    int fgrp = (lane & 15) * 4;    // first of this lane's 4 features
    const unsigned char* zp = z8 + fgrp;
    float4 bi4 = *(const float4*)(bias + fgrp);

    int n = wave;
    if (n >= NN) return;
    n = __builtin_amdgcn_readfirstlane(n);
    int off = offs[n];
    int dg = deg[n];
    float edn = ed[n];
    int sv = src_sorted[off + ((lane < dg) ? lane : 0)];   // first batch src
    float ese = es[sv];                                    // first batch es

    while (true) {
        // Issue next node's metadata loads early (overlap with processing)
        int n2 = n + NW;
        bool more = (n2 < NN);
        int off2 = 0, dg2 = 0; float edn2 = 0.f;
        if (more) {
            n2 = __builtin_amdgcn_readfirstlane(n2);
            off2 = offs[n2]; dg2 = deg[n2]; edn2 = ed[n2];
        }

        // ---- process node n ----
        float dsum = 0.f;
        float a0 = 0.f, a1 = 0.f, a2 = 0.f, a3 = 0.f;
        for (int b0 = 0; b0 < dg; b0 += 64) {
            int bl = dg - b0; if (bl > 64) bl = 64;
            int svb; float esv;
            if (b0 == 0) { svb = sv; esv = ese; }          // prefetched
            else {
                svb = src_sorted[off + b0 + ((lane < bl) ? lane : 0)];
                esv = es[svb];
            }
            float e = esv + edn;
            e = (e > 0.f) ? e : 0.2f * e;
            float w = (lane < bl) ? __expf(e) : 0.f;   // w=0 pads tail edges
            dsum += w;

            // publish this batch's (w, byte-offset) pairs: one ds_write_b64
            swl[wslot][lane] = ((unsigned long long)__float_as_uint(w) << 32)
                             | (unsigned)(svb << 6);

            int ng = (bl + 3) >> 2;        // 4-edge groups in this batch
            int j = 0;
            for (; j + 4 <= ng; j += 4) {  // 16 edges, 4 loads in flight
                int i0 = 4 * j + sub;
                unsigned long long p0 = swl[wslot][i0];
                unsigned long long p1 = swl[wslot][i0 + 4];
                unsigned long long p2 = swl[wslot][i0 + 8];
                unsigned long long p3 = swl[wslot][i0 + 12];
                unsigned int v0 = *(const unsigned int*)(zp + (unsigned)p0);
                unsigned int v1 = *(const unsigned int*)(zp + (unsigned)p1);
                unsigned int v2 = *(const unsigned int*)(zp + (unsigned)p2);
                unsigned int v3 = *(const unsigned int*)(zp + (unsigned)p3);
                float w0 = __uint_as_float((unsigned)(p0 >> 32));
                float w1 = __uint_as_float((unsigned)(p1 >> 32));
                float w2 = __uint_as_float((unsigned)(p2 >> 32));
                float w3 = __uint_as_float((unsigned)(p3 >> 32));
                a0 = fmaf(w0, CVT_FP8(v0, 0), a0);
                a1 = fmaf(w0, CVT_FP8(v0, 1), a1);
                a2 = fmaf(w0, CVT_FP8(v0, 2), a2);
                a3 = fmaf(w0, CVT_FP8(v0, 3), a3);
                a0 = fmaf(w1, CVT_FP8(v1, 0), a0);
                a1 = fmaf(w1, CVT_FP8(v1, 1), a1);
                a2 = fmaf(w1, CVT_FP8(v1, 2), a2);
                a3 = fmaf(w1, CVT_FP8(v1, 3), a3);
                a0 = fmaf(w2, CVT_FP8(v2, 0), a0);
                a1 = fmaf(w2, CVT_FP8(v2, 1), a1);
                a2 = fmaf(w2, CVT_FP8(v2, 2), a2);
                a3 = fmaf(w2, CVT_FP8(v2, 3), a3);
                a0 = fmaf(w3, CVT_FP8(v3, 0), a0);
                a1 = fmaf(w3, CVT_FP8(v3, 1), a1);
                a2 = fmaf(w3, CVT_FP8(v3, 2), a2);
                a3 = fmaf(w3, CVT_FP8(v3, 3), a3);
            }
            for (; j < ng; ++j) {          // remaining 4-edge groups
                int i0 = 4 * j + sub;
                unsigned long long p0 = swl[wslot][i0];
                unsigned int v0 = *(const unsigned int*)(zp + (unsigned)p0);
                float w0 = __uint_as_float((unsigned)(p0 >> 32));
                a0 = fmaf(w0, CVT_FP8(v0, 0), a0);
                a1 = fmaf(w0, CVT_FP8(v0, 1), a1);
                a2 = fmaf(w0, CVT_FP8(v0, 2), a2);
                a3 = fmaf(w0, CVT_FP8(v0, 3), a3);
            }
        }

        // Prefetch next node's first src batch (hides behind epilogue)
        int sv2 = 0;
        if (more) sv2 = src_sorted[off2 + ((lane < dg2) ? lane : 0)];

        // Epilogue: fold edge-subsets (lanes l, l+16, l+32, l+48), reduce denom
        a0 += __shfl_xor(a0, 16); a1 += __shfl_xor(a1, 16);
        a2 += __shfl_xor(a2, 16); a3 += __shfl_xor(a3, 16);
        a0 += __shfl_xor(a0, 32); a1 += __shfl_xor(a1, 32);
        a2 += __shfl_xor(a2, 32); a3 += __shfl_xor(a3, 32);
#pragma unroll
        for (int d = 32; d; d >>= 1) dsum += __shfl_xor(dsum, d);

        // Prefetch next node's es gather
        float ese2 = 0.f;
        if (more) ese2 = es[sv2];

        float inv = 1.f / (dsum + 1e-16f);
        if (lane < 16) {
            float4 o;
            o.x = a0 * inv + bi4.x;
            o.y = a1 * inv + bi4.y;
            o.z = a2 * inv + bi4.z;
            o.w = a3 * inv + bi4.w;
            o.x = (o.x > 0.f) ? o.x : 0.01f * o.x;
            o.y = (o.y > 0.f) ? o.y : 0.01f * o.y;
            o.z = (o.z > 0.f) ? o.z : 0.01f * o.z;
            o.w = (o.w > 0.f) ? o.w : 0.01f * o.w;
            *(float4*)(hout + (size_t)n * 64 + fgrp) = o;
        }
        if (lane == 0) denom_out[n] = dsum;

        if (!more) break;
        n = n2; off = off2; dg = dg2; edn = edn2; sv = sv2; ese = ese2;
    }
}

// ---------------------------------------------------------------------------
// Alpha in ORIGINAL edge order: contiguous writes, L2-resident gathers.
// ---------------------------------------------------------------------------
__global__ __launch_bounds__(256) void alpha_kernel(const int* __restrict__ ei,
                                                    const float* __restrict__ es,
                                                    const float* __restrict__ ed,
                                                    const float* __restrict__ denom,
                                                    float* __restrict__ alpha_out) {
    int e = blockIdx.x * 256 + threadIdx.x;
    if (e >= E2) return;
    int s, d;
    if (e < EE) { s = ei[e]; d = ei[EE + e]; }
    else        { s = d = e - EE; }
    float x = es[s] + ed[d];
    x = (x > 0.f) ? x : 0.2f * x;
    alpha_out[e] = __expf(x) / (denom[d] + 1e-16f);
}

// ---------------------------------------------------------------------------
extern "C" void kernel_launch(void* const* d_in, const int* in_sizes, int n_in,
                              void* d_out, int out_size, void* d_ws, size_t ws_size,
                              hipStream_t stream) {
    const float* x   = (const float*)d_in[0];
    const int*   ei  = (const int*)d_in[1];
    const float* W1  = (const float*)d_in[2];
    const float* as1 = (const float*)d_in[3];
    const float* ad1 = (const float*)d_in[4];
    const float* b1  = (const float*)d_in[5];
    const float* W2  = (const float*)d_in[6];
    const float* as2 = (const float*)d_in[7];
    const float* ad2 = (const float*)d_in[8];
    const float* b2  = (const float*)d_in[9];
    const float* W3  = (const float*)d_in[10];
    const float* as3 = (const float*)d_in[11];
    const float* ad3 = (const float*)d_in[12];
    const float* b3  = (const float*)d_in[13];

    // d_out is float32 (reference output dtype): h | ei | alpha, flat.
    float* out       = (float*)d_out;
    float* h_out     = out;                                // NN*64
    float* ei_out    = out + (size_t)NN * 64;              // 2*E2
    float* alpha_out = ei_out + 2 * (size_t)E2;            // E2

    // Workspace carve-up
    char* w = (char*)d_ws;
    auto carve = [&](size_t bytes) {
        void* p = (void*)w;
        w += (bytes + 255) & ~size_t(255);
        return p;
    };
    float* h1  = (float*)carve((size_t)NN * 64 * 4);
    float* h2  = (float*)carve((size_t)NN * 64 * 4);
    unsigned char* z8 = (unsigned char*)carve((size_t)NN * 64);
    float* es  = (float*)carve((size_t)NN * 4);
    float* ed  = (float*)carve((size_t)NN * 4);
    float* denom = (float*)carve((size_t)NN * 4);
    int* deg        = (int*)carve(((size_t)NN + 64) * 4);  // deg + ticket (zeroed together)
    int* ticket     = deg + NN;
    int* offs       = (int*)carve((size_t)NN * 4);
    int* cursor     = (int*)carve((size_t)NN * 4);
    int* csum       = (int*)carve((size_t)NCHUNK * 4);
    int* src_sorted = (int*)carve((size_t)E2 * 4);

    const int EB = (E2 + 255) / 256;       // 3321

    hipMemsetAsync(deg, 0, ((size_t)NN + 64) * 4, stream);
    hist_ei_kernel<<<EB, 256, 0, stream>>>(ei, deg, ei_out);
    scan_part12<<<NCHUNK, 256, 0, stream>>>(deg, csum, ticket);
    scan_part3<<<NCHUNK, 256, 0, stream>>>(deg, csum, offs, cursor);
    scatter_kernel<<<SLICES * 8, 256, 0, stream>>>(ei, cursor, src_sorted);

    // Layer 1: x (K=128) -> h1
    gemm_tile<F_IN><<<NTILE, 256, 0, stream>>>(x, W1, as1, ad1, z8, es, ed);
    aggregate<<<AGGB, 256, 0, stream>>>(offs, deg, src_sorted, es, ed, z8, b1, h1, denom);
    // Layer 2: h1 (K=64) -> h2
    gemm_tile<F_HID><<<NTILE, 256, 0, stream>>>(h1, W2, as2, ad2, z8, es, ed);
    aggregate<<<AGGB, 256, 0, stream>>>(offs, deg, src_sorted, es, ed, z8, b2, h2, denom);
    // Layer 3: h2 (K=64) -> d_out h (fp32) + alpha
    gemm_tile<F_HID><<<NTILE, 256, 0, stream>>>(h2, W3, as3, ad3, z8, es, ed);
    aggregate<<<AGGB, 256, 0, stream>>>(offs, deg, src_sorted, es, ed, z8, b3, h_out, denom);
    alpha_kernel<<<EB, 256, 0, stream>>>(ei, es, ed, denom, alpha_out);
}